// Round 19
// baseline (429.850 us; speedup 1.0000x reference)
//
#include <hip/hip_runtime.h>

typedef __bf16 bf16x8 __attribute__((ext_vector_type(8)));
typedef __bf16 bf16x4 __attribute__((ext_vector_type(4)));
typedef float  f32x4  __attribute__((ext_vector_type(4)));

#define T_TOT 4096
#define SEQ   1024
#define BATCH 4
#define HEADS 16
#define DIM   128
#define HIDN  2048
#define QKVW  6144

__device__ __forceinline__ void gld_lds16(const void* g, void* l) {
  __builtin_amdgcn_global_load_lds(
      (const __attribute__((address_space(1))) unsigned int*)g,
      (__attribute__((address_space(3))) unsigned int*)l, 16, 0, 0);
}

// ---------------- merged f32 -> bf16 conversions (one launch) ----------------
__global__ void f2b_all(const float* __restrict__ h,  __bf16* __restrict__ oh,
                        const float* __restrict__ wa, __bf16* __restrict__ owa,
                        const float* __restrict__ wp, __bf16* __restrict__ owp)
{
  const int bid = blockIdx.x;
  const float* in;
  __bf16* out;
  int base;
  if (bid < 8192)       { in = h;  out = oh;  base = bid; }
  else if (bid < 20480) { in = wa; out = owa; base = bid - 8192; }
  else                  { in = wp; out = owp; base = bid - 20480; }
  const int i = (base * 256 + threadIdx.x) * 4;
  const float4 v = *(const float4*)(in + i);
  bf16x4 o;
  o[0] = (__bf16)v.x; o[1] = (__bf16)v.y; o[2] = (__bf16)v.z; o[3] = (__bf16)v.w;
  *(bf16x4*)(out + i) = o;
}

// ======== gemm_qkv (GEMM1 + fused bias/RoPE/pack): BM=256 BN=128 BK=32 ========
// Main loop = PROVEN round-15 gemm_wide (128us): 4 waves, wave-tile 128x64,
// 72KB triple-buffer, lead-2 counted vmcnt(6), ONE barrier/tile, frag
// prefetch after barrier. Epilogue fused: 128-col tile == one head (region
// and h are block-uniform). Q/K: RoPE pair (d,d+64) spans the two wn-waves ->
// exchange per-n 16-col slice through sA (dead after K-loop) as bf16.
// V: direct transposed store to Vt[bh][d][s].
__global__ __launch_bounds__(256, 2) void gemm_qkv(
    const __bf16* __restrict__ A,      // hid_bf [4096][2048]
    const __bf16* __restrict__ B,      // wattn_bf [6144][2048]
    const float* __restrict__ bias,    // [6144]
    const float* __restrict__ cosb,    // [4096][64]
    const float* __restrict__ sinb,
    __bf16* __restrict__ Qp,           // [64][1024][128]
    __bf16* __restrict__ Kp,
    __bf16* __restrict__ Vt)           // [64][128][1024]
{
  __shared__ __bf16 sA[3 * 256 * 32];   // 48 KB
  __shared__ __bf16 sB[3 * 128 * 32];   // 24 KB
  const int lda = HIDN, ldb = HIDN;
  const int tid = threadIdx.x;
  const int w = tid >> 6, lane = tid & 63;
  const int lq = lane & 15, lg = lane >> 4;
  const int wm = w >> 1, wn = w & 1;

  // bijective XCD swizzle (768 % 8 == 0); M-major chunks per XCD
  const int nwg = gridDim.x, cpx = nwg >> 3, bid = blockIdx.x;
  const int wgid = (bid & 7) * cpx + (bid >> 3);
  const int by = wgid % 16, bx = wgid / 16;      // by 0..15, bx 0..47
  const int bm = by * 256, bn = bx * 128;

  // staging: one issue = 256 thr x 16B = 64 rows x 64B
  const int srow = tid >> 2;
  const int scol = ((tid & 3) ^ ((srow >> 1) & 3)) * 8;  // pre-swizzled col
  const __bf16* gA = A + (size_t)(bm + srow) * lda + scol;
  const __bf16* gB = B + (size_t)(bn + srow) * ldb + scol;
  __bf16* dA = &sA[w * 512];
  __bf16* dB = &sB[w * 512];

  const int NT = HIDN >> 5;   // 64

#define STAGE(t, bf) {                                               \
    const __bf16* sa_ = gA + (size_t)(t) * 32;                       \
    gld_lds16(sa_,                      dA + (bf) * 8192);           \
    gld_lds16(sa_ + (size_t) 64 * lda,  dA + (bf) * 8192 + 2048);    \
    gld_lds16(sa_ + (size_t)128 * lda,  dA + (bf) * 8192 + 4096);    \
    gld_lds16(sa_ + (size_t)192 * lda,  dA + (bf) * 8192 + 6144);    \
    const __bf16* sb_ = gB + (size_t)(t) * 32;                       \
    gld_lds16(sb_,                      dB + (bf) * 4096);           \
    gld_lds16(sb_ + (size_t) 64 * ldb,  dB + (bf) * 4096 + 2048); }

  f32x4 acc[8][4] = {};

  // ds_read: stored granule = lg ^ ((row>>1)&3); row = base16 + lq
  const int colo = (lg ^ ((lq >> 1) & 3)) * 8;
  const int offA = (wm * 128 + lq) * 32 + colo;
  const int offB = (wn * 64 + lq) * 32 + colo;

  STAGE(0, 0); STAGE(1, 1);
  asm volatile("s_waitcnt vmcnt(6)" ::: "memory");   // tile0 landed
  __builtin_amdgcn_s_barrier();
  asm volatile("" ::: "memory");

  bf16x8 a[8], b[4];
  {
    const __bf16* pA = &sA[offA];
    const __bf16* pB = &sB[offB];
#pragma unroll
    for (int m = 0; m < 8; ++m) a[m] = *(const bf16x8*)(pA + m * 512);
#pragma unroll
    for (int n = 0; n < 4; ++n) b[n] = *(const bf16x8*)(pB + n * 512);
  }

  int bcur = 0;
  for (int t = 0; t < NT; ++t) {
    int bstg = bcur + 2; if (bstg >= 3) bstg -= 3;
    const bool st = (t + 2) < NT;
    if (st) STAGE(t + 2, bstg);

    asm volatile("s_waitcnt lgkmcnt(0)" ::: "memory");
    __builtin_amdgcn_sched_barrier(0);
    __builtin_amdgcn_s_setprio(1);
#pragma unroll
    for (int m = 0; m < 8; ++m)
#pragma unroll
      for (int n = 0; n < 4; ++n)
        acc[m][n] = __builtin_amdgcn_mfma_f32_16x16x32_bf16(a[m], b[n], acc[m][n], 0, 0, 0);
    __builtin_amdgcn_s_setprio(0);

    if (t + 1 < NT) {
      if (st) { asm volatile("s_waitcnt vmcnt(6)" ::: "memory"); }
      else    { asm volatile("s_waitcnt vmcnt(0)" ::: "memory"); }
      __builtin_amdgcn_s_barrier();
      asm volatile("" ::: "memory");
      const int bnext = (bcur + 1 == 3) ? 0 : bcur + 1;
      const __bf16* pA = &sA[bnext * 8192 + offA];
      const __bf16* pB = &sB[bnext * 4096 + offB];
#pragma unroll
      for (int m = 0; m < 8; ++m) a[m] = *(const bf16x8*)(pA + m * 512);
#pragma unroll
      for (int n = 0; n < 4; ++n) b[n] = *(const bf16x8*)(pB + n * 512);
    }
    bcur = (bcur + 1 == 3) ? 0 : bcur + 1;
  }
#undef STAGE

  // ---- fused epilogue: bias + RoPE + pack ----
  const int region = bx >> 4;     // 0=Q 1=K 2=V  (block-uniform)
  const int h = bx & 15;
  if (region == 2) {
    // V: bias + transposed store Vt[bh][d][s]
#pragma unroll
    for (int n = 0; n < 4; ++n) {
      const int col = bn + wn * 64 + n * 16 + lq;   // 4096 + h*128 + d
      const int d = wn * 64 + n * 16 + lq;
      const float bv = bias[col];
#pragma unroll
      for (int m = 0; m < 8; ++m) {
        const int row = bm + wm * 128 + m * 16 + lg * 4;
        const int b_ = row >> 10, s0 = row & 1023;
        bf16x4 o;
#pragma unroll
        for (int r = 0; r < 4; ++r) o[r] = (__bf16)(acc[m][n][r] + bv);
        *(bf16x4*)&Vt[((size_t)(b_ * 16 + h) * 128 + d) * 1024 + s0] = o;
      }
    }
  } else {
    // Q/K: exchange (d, d+64) partner through sA scratch, then RoPE + store
    __bf16* scr = sA;                        // [2][256][16] bf16 = 16 KB
    __bf16* Dst = region ? Kp : Qp;
    const float qs = region ? 1.0f : 0.08838834764831845f;  // Q pre-scale
    __syncthreads();                         // all waves done with sA/sB reads
#pragma unroll
    for (int n = 0; n < 4; ++n) {
      const int j = n * 16 + lq;             // rope lane 0..63 (== d & 63)
      const float bv = bias[bn + wn * 64 + j];
#pragma unroll
      for (int m = 0; m < 8; ++m)
#pragma unroll
        for (int r = 0; r < 4; ++r) {
          const int rl = wm * 128 + m * 16 + lg * 4 + r;
          scr[(wn * 256 + rl) * 16 + lq] = (__bf16)(acc[m][n][r] + bv);
        }
      __syncthreads();
#pragma unroll
      for (int m = 0; m < 8; ++m)
#pragma unroll
        for (int r = 0; r < 4; ++r) {
          const int rl = wm * 128 + m * 16 + lg * 4 + r;
          const int t = bm + rl;             // global token
          const float own = acc[m][n][r] + bv;
          const float prt = (float)scr[((wn ^ 1) * 256 + rl) * 16 + lq];
          const float c  = cosb[(size_t)t * 64 + j];
          const float sn = sinb[(size_t)t * 64 + j];
          // wn==0 holds x1 (out = x1*c - x2*s); wn==1 holds x2 (out = x2*c + x1*s)
          const float o = (wn == 0 ? own * c - prt * sn : own * c + prt * sn) * qs;
          const int b_ = t >> 10, s = t & 1023;
          Dst[((size_t)(b_ * 16 + h) * 1024 + s) * 128 + wn * 64 + j] = (__bf16)o;
        }
      __syncthreads();
    }
  }
}

// ======== gemm_sq (GEMM2, PROVEN round-15): BM=BN=128 BK=32, 64x64 wave-tile ====
template<int BIAS, typename OUT_T>
__global__ __launch_bounds__(256, 3) void gemm_sq(
    const __bf16* __restrict__ A, int lda,
    const __bf16* __restrict__ B, int ldb,
    const float* __restrict__ bias,
    OUT_T* __restrict__ C, int ldc, int K, int nby)
{
  __shared__ __bf16 sA[3 * 128 * 32];   // 24 KB
  __shared__ __bf16 sB[3 * 128 * 32];   // 24 KB
  const int tid = threadIdx.x;
  const int w = tid >> 6, lane = tid & 63;
  const int lq = lane & 15, lg = lane >> 4;
  const int wm = w >> 1, wn = w & 1;

  const int nwg = gridDim.x, cpx = nwg >> 3, bid = blockIdx.x;
  const int wgid = (bid & 7) * cpx + (bid >> 3);
  const int by = wgid % nby, bx = wgid / nby;
  const int bm = by * 128, bn = bx * 128;

  const int srow = tid >> 2;
  const int scol = ((tid & 3) ^ ((srow >> 1) & 3)) * 8;
  const __bf16* gA = A + (size_t)(bm + srow) * lda + scol;
  const __bf16* gB = B + (size_t)(bn + srow) * ldb + scol;
  const int w16 = w * 16;
  const int NT = K >> 5;

#define STAGE(t, bf) {                                                    \
    const __bf16* sa_ = gA + (size_t)(t) * 32;                            \
    gld_lds16(sa_,                     &sA[(bf) * 4096 + (w16) * 32]);    \
    gld_lds16(sa_ + (size_t)64 * lda,  &sA[(bf) * 4096 + (64 + w16) * 32]); \
    const __bf16* sb_ = gB + (size_t)(t) * 32;                            \
    gld_lds16(sb_,                     &sB[(bf) * 4096 + (w16) * 32]);    \
    gld_lds16(sb_ + (size_t)64 * ldb,  &sB[(bf) * 4096 + (64 + w16) * 32]); }

  f32x4 acc[4][4] = {};

  const int colo = (lg ^ ((lq >> 1) & 3)) * 8;
  const int offA = (wm * 64 + lq) * 32 + colo;
  const int offB = (wn * 64 + lq) * 32 + colo;

  STAGE(0, 0); STAGE(1, 1);
  asm volatile("s_waitcnt vmcnt(4)" ::: "memory");
  __builtin_amdgcn_s_barrier();
  asm volatile("" ::: "memory");

  bf16x8 a[4], b[4];
  {
    const __bf16* pA = &sA[offA];
    const __bf16* pB = &sB[offB];
#pragma unroll
    for (int m = 0; m < 4; ++m) a[m] = *(const bf16x8*)(pA + m * 512);
#pragma unroll
    for (int n = 0; n < 4; ++n) b[n] = *(const bf16x8*)(pB + n * 512);
  }

  int bcur = 0;
  for (int t = 0; t < NT; ++t) {
    int bstg = bcur + 2; if (bstg >= 3) bstg -= 3;
    const bool st = (t + 2) < NT;
    if (st) STAGE(t + 2, bstg);

    asm volatile("s_waitcnt lgkmcnt(0)" ::: "memory");
    __builtin_amdgcn_sched_barrier(0);
    __builtin_amdgcn_s_setprio(1);
#pragma unroll
    for (int m = 0; m < 4; ++m)
#pragma unroll
      for (int n = 0; n < 4; ++n)
        acc[m][n] = __builtin_amdgcn_mfma_f32_16x16x32_bf16(a[m], b[n], acc[m][n], 0, 0, 0);
    __builtin_amdgcn_s_setprio(0);

    if (t + 1 < NT) {
      if (st) { asm volatile("s_waitcnt vmcnt(4)" ::: "memory"); }
      else    { asm volatile("s_waitcnt vmcnt(0)" ::: "memory"); }
      __builtin_amdgcn_s_barrier();
      asm volatile("" ::: "memory");
      const int bnext = (bcur + 1 == 3) ? 0 : bcur + 1;
      const __bf16* pA = &sA[bnext * 4096 + offA];
      const __bf16* pB = &sB[bnext * 4096 + offB];
#pragma unroll
      for (int m = 0; m < 4; ++m) a[m] = *(const bf16x8*)(pA + m * 512);
#pragma unroll
      for (int n = 0; n < 4; ++n) b[n] = *(const bf16x8*)(pB + n * 512);
    }
    bcur = (bcur + 1 == 3) ? 0 : bcur + 1;
  }
#undef STAGE

#pragma unroll
  for (int n = 0; n < 4; ++n) {
    const int col = bn + wn * 64 + n * 16 + lq;
    const float bv = BIAS ? bias[col] : 0.0f;
#pragma unroll
    for (int m = 0; m < 4; ++m)
#pragma unroll
      for (int r = 0; r < 4; ++r) {
        const int row = bm + wm * 64 + m * 16 + lg * 4 + r;
        C[(size_t)row * ldc + col] = (OUT_T)(acc[m][n][r] + bv);
      }
  }
}

// ---------------- causal flash attention v3 (unchanged, proven) ----------------
__global__ __launch_bounds__(256, 2) void attn_kernel(const __bf16* __restrict__ Qp,
                                                      const __bf16* __restrict__ Kp,
                                                      const __bf16* __restrict__ Vt,
                                                      __bf16* __restrict__ O)
{
  __shared__ __bf16 sK[2][64 * 128];   // 32 KB
  __shared__ __bf16 sV[2][128 * 64];   // 32 KB
  __shared__ __bf16 sP[4][32 * 64];    // 16 KB (XOR-swizzled)
  const int w = threadIdx.x >> 6, lane = threadIdx.x & 63;
  const int lq = lane & 15, lg = lane >> 4;
  const int bh = blockIdx.y, b = bh >> 4, h = bh & 15;
  const int qb = ((int)blockIdx.x + bh) & 7;
  const int q0 = qb * 128 + w * 32;
  const int NTb = 2 * qb + 2;
  const int kend = q0 + 32;

  const __bf16* Qh = Qp + (size_t)bh * SEQ * DIM;
  const __bf16* Kh = Kp + (size_t)bh * SEQ * DIM;
  const __bf16* Vh = Vt + (size_t)bh * DIM * SEQ;

  const int krow = lane >> 4;
  const int kgr  = lane & 15;
  const int vrow = lane >> 3;
  const int vgr  = lane & 7;
  const __bf16* Vsrc = Vh + (size_t)(w * 32 + vrow) * SEQ + (vgr ^ vrow) * 8;

  auto ASTAGE = [&](int ktn, int p) {
#pragma unroll
    for (int i = 0; i < 4; ++i) {
      const int rb = w * 16 + i * 4;
      gld_lds16(Kh + (size_t)(ktn + rb + krow) * DIM + (kgr ^ (i * 4 + krow)) * 8,
                &sK[p][rb * DIM]);
    }
#pragma unroll
    for (int i = 0; i < 4; ++i) {
      gld_lds16(Vsrc + (size_t)i * 8 * SEQ + ktn, &sV[p][(w * 32 + i * 8) * 64]);
    }
  };

  bf16x8 aq[2][4];
#pragma unroll
  for (int m = 0; m < 2; ++m)
#pragma unroll
    for (int kk = 0; kk < 4; ++kk)
      aq[m][kk] = *(const bf16x8*)(Qh + (size_t)(q0 + m * 16 + lq) * DIM + kk * 32 + lg * 8);

  f32x4 accO[2][8] = {};
  float mrow[2][4], lrow[2][4];
#pragma unroll
  for (int m = 0; m < 2; ++m)
#pragma unroll
    for (int r = 0; r < 4; ++r) { mrow[m][r] = -1e30f; lrow[m][r] = 0.0f; }

  ASTAGE(0, 0);
  asm volatile("s_waitcnt vmcnt(0)" ::: "memory");
  __builtin_amdgcn_s_barrier();

  int p = 0;
  for (int t = 0; t < NTb; ++t) {
    const int kt = t * 64;
    if (t + 1 < NTb) ASTAGE(kt + 64, p ^ 1);

    if (kt < kend) {
      f32x4 s[2][4] = {};
#pragma unroll
      for (int n = 0; n < 4; ++n) {
        const int rowb = (n * 16 + lq) * DIM;
#pragma unroll
        for (int kk = 0; kk < 4; ++kk) {
          const bf16x8 bk = *(const bf16x8*)&sK[p][rowb + ((4 * kk + lg) ^ lq) * 8];
#pragma unroll
          for (int m = 0; m < 2; ++m)
            s[m][n] = __builtin_amdgcn_mfma_f32_16x16x32_bf16(aq[m][kk], bk, s[m][n], 0, 0, 0);
        }
      }
      if (kt + 63 > q0) {
#pragma unroll
        for (int n = 0; n < 4; ++n) {
          const int kpos = kt + n * 16 + lq;
#pragma unroll
          for (int m = 0; m < 2; ++m)
#pragma unroll
            for (int r = 0; r < 4; ++r)
              if (kpos > q0 + m * 16 + lg * 4 + r) s[m][n][r] = -1e30f;
        }
      }
#pragma unroll
      for (int m = 0; m < 2; ++m) {
#pragma unroll
        for (int r = 0; r < 4; ++r) {
          float mx = fmaxf(fmaxf(s[m][0][r], s[m][1][r]), fmaxf(s[m][2][r], s[m][3][r]));
          mx = fmaxf(mx, __shfl_xor(mx, 1));
          mx = fmaxf(mx, __shfl_xor(mx, 2));
          mx = fmaxf(mx, __shfl_xor(mx, 4));
          mx = fmaxf(mx, __shfl_xor(mx, 8));
          const float mnew = fmaxf(mrow[m][r], mx);
          const float alpha = __expf(mrow[m][r] - mnew);
          mrow[m][r] = mnew;
          float rs = 0.0f;
#pragma unroll
          for (int n = 0; n < 4; ++n) {
            const float pv = __expf(s[m][n][r] - mnew);
            s[m][n][r] = pv;
            rs += pv;
          }
          rs += __shfl_xor(rs, 1); rs += __shfl_xor(rs, 2);
          rs += __shfl_xor(rs, 4); rs += __shfl_xor(rs, 8);
          lrow[m][r] = lrow[m][r] * alpha + rs;
#pragma unroll
          for (int f = 0; f < 8; ++f) accO[m][f][r] *= alpha;
        }
      }
#pragma unroll
      for (int m = 0; m < 2; ++m)
#pragma unroll
        for (int n = 0; n < 4; ++n)
#pragma unroll
          for (int r = 0; r < 4; ++r) {
            const int prow = m * 16 + lg * 4 + r;
            const int cb = (n * 16 + lq) * 2;
            const int addr = prow * 128 + (((cb >> 4) ^ (prow & 7)) << 4) + (cb & 15);
            *(__bf16*)((char*)&sP[w][0] + addr) = (__bf16)s[m][n][r];
          }
      asm volatile("s_waitcnt lgkmcnt(0)" ::: "memory");
#pragma unroll
      for (int kk2 = 0; kk2 < 2; ++kk2) {
        bf16x8 ap[2];
#pragma unroll
        for (int m = 0; m < 2; ++m) {
          const int prow = m * 16 + lq;
          ap[m] = *(const bf16x8*)((char*)&sP[w][0] +
                   prow * 128 + (((4 * kk2 + lg) ^ (lq & 7)) << 4));
        }
#pragma unroll
        for (int f = 0; f < 8; ++f) {
          const bf16x8 bv = *(const bf16x8*)&sV[p][(f * 16 + lq) * 64 +
                                                   ((4 * kk2 + lg) ^ (lq & 7)) * 8];
#pragma unroll
          for (int m = 0; m < 2; ++m)
            accO[m][f] = __builtin_amdgcn_mfma_f32_16x16x32_bf16(ap[m], bv, accO[m][f], 0, 0, 0);
        }
      }
    }
    asm volatile("s_waitcnt vmcnt(0)" ::: "memory");
    __builtin_amdgcn_s_barrier();
    p ^= 1;
  }

#pragma unroll
  for (int m = 0; m < 2; ++m)
#pragma unroll
    for (int f = 0; f < 8; ++f)
#pragma unroll
      for (int r = 0; r < 4; ++r) {
        const float v = accO[m][f][r] / lrow[m][r];
        O[((size_t)b * SEQ + q0 + m * 16 + lg * 4 + r) * HIDN + h * DIM + f * 16 + lq] = (__bf16)v;
      }
}

// ---------------- launch ----------------
extern "C" void kernel_launch(void* const* d_in, const int* in_sizes, int n_in,
                              void* d_out, int out_size, void* d_ws, size_t ws_size,
                              hipStream_t stream)
{
  const float* hidden = (const float*)d_in[0];
  const float* cosb   = (const float*)d_in[1];
  const float* sinb   = (const float*)d_in[2];
  const float* w_attn = (const float*)d_in[3];
  const float* b_attn = (const float*)d_in[4];
  const float* w_proj = (const float*)d_in[5];

  char* ws = (char*)d_ws;
  __bf16* hid_bf   = (__bf16*)(ws);                 // [0, 16M)
  __bf16* wattn_bf = (__bf16*)(ws + 16777216);      // [16M, 40M)
  __bf16* wproj_bf = (__bf16*)(ws + 41943040);      // [40M, 48M)
  __bf16* Qp       = (__bf16*)(ws + 50331648);      // [48M, 64M)
  __bf16* Kp       = (__bf16*)(ws + 67108864);      // [64M, 80M)
  __bf16* Vt       = (__bf16*)(ws + 83886080);      // [80M, 96M)
  __bf16* Obuf     = (__bf16*)(ws + 100663296);     // [96M, 112M)
  float* out = (float*)d_out;

  f2b_all<<<24576, 256, 0, stream>>>(hidden, hid_bf, w_attn, wattn_bf, w_proj, wproj_bf);

  // fused GEMM1 + bias + RoPE + pack: writes Qp/Kp/Vt directly (no qkv buffer)
  gemm_qkv<<<768, 256, 0, stream>>>(
      hid_bf, wattn_bf, b_attn, cosb, sinb, Qp, Kp, Vt);

  attn_kernel<<<dim3(8, 64), 256, 0, stream>>>(Qp, Kp, Vt, Obuf);

  // out = O @ w_proj^T   (M=4096, N=2048, K=2048): 32x16 = 512 blocks, f32 out
  gemm_sq<0, float><<<512, 256, 0, stream>>>(
      Obuf, HIDN, wproj_bf, HIDN, nullptr, out, HIDN, HIDN, 32);
}